// Round 1
// baseline (64.939 us; speedup 1.0000x reference)
//
#include <hip/hip_runtime.h>

// out[b] = cos(x[b,0]).
//
// Derivation: initial state is a real product state (per-wire normalized
// [cos(x_i/2), sin(x_i/2)]). RZ layers are unit-modulus diagonal phases
// (magnitude-preserving); CNOTs are amplitude permutations whose targets are
// wires 1..3 only, so the wire-0 bit of every basis index is invariant.
// |state|^2 is thus the initial probability tensor permuted within the
// (b1,b2,b3) sub-index for each fixed b0; summing probs * (-1)^{b0}
// marginalizes wires 1..3 (each sums to 1) leaving
// cos^2(x0/2) - sin^2(x0/2) = cos(x0). Weight cancels entirely.

__global__ __launch_bounds__(256) void quanv_cos_kernel(
    const float4* __restrict__ x,   // (B,4) viewed as B float4s
    float* __restrict__ out,        // (B,)
    int n)
{
    int i = blockIdx.x * blockDim.x + threadIdx.x;
    if (i < n) {
        float4 v = x[i];            // coalesced 16B/lane; we only need v.x
        out[i] = cosf(v.x);
    }
}

extern "C" void kernel_launch(void* const* d_in, const int* in_sizes, int n_in,
                              void* d_out, int out_size, void* d_ws, size_t ws_size,
                              hipStream_t stream) {
    const float4* x = (const float4*)d_in[0];   // (B,4) fp32
    float* out = (float*)d_out;                 // (B,) fp32
    int n = out_size;                           // B = 1048576

    const int block = 256;
    const int grid = (n + block - 1) / block;
    quanv_cos_kernel<<<grid, block, 0, stream>>>(x, out, n);
}